// Round 10
// baseline (251.333 us; speedup 1.0000x reference)
//
#include <hip/hip_runtime.h>
#include <stdint.h>
#include <math.h>

typedef __attribute__((ext_vector_type(8))) __bf16 bf16x8;
typedef __attribute__((ext_vector_type(4))) __bf16 bf16x4;
typedef __attribute__((ext_vector_type(4))) float f32x4;
typedef __attribute__((ext_vector_type(16))) float f32x16;

#define MFMA16(A, B, C) __builtin_amdgcn_mfma_f32_16x16x32_bf16((A), (B), (C), 0, 0, 0)
#define MFMA32(A, B, C) __builtin_amdgcn_mfma_f32_32x32x16_bf16((A), (B), (C), 0, 0, 0)

#if defined(__has_builtin)
#if __has_builtin(__builtin_amdgcn_exp2f)
#define EXP2(x) __builtin_amdgcn_exp2f(x)
#else
#define EXP2(x) exp2f(x)
#endif
#else
#define EXP2(x) exp2f(x)
#endif

static constexpr int kT  = 2048;
static constexpr int kC  = 1024;
static constexpr int kHD = 64;
// q pre-scale: (1/sqrt(64)) * log2(e) so exp2(s') == exp(q.k/8)
#define QSCALE 0.1803368801111204f

__device__ __forceinline__ void g2l16(const void* g, void* l) {
  __builtin_amdgcn_global_load_lds(
      (const __attribute__((address_space(1))) uint32_t*)g,
      (__attribute__((address_space(3))) uint32_t*)l, 16, 0, 0);
}

// -------- fused prep: x f32->bf16 | W_attn^T | W_proj^T (one launch) --------
__global__ __launch_bounds__(256) void k_prep(const float* __restrict__ x,
                                              __bf16* __restrict__ xb,
                                              const float* __restrict__ Wa,
                                              __bf16* __restrict__ wab,
                                              const float* __restrict__ Wp,
                                              __bf16* __restrict__ wpb) {
  const int bid = (int)blockIdx.x;
  const int tid = threadIdx.x;
  if (bid < 8192) {
    int i = (bid * 256 + tid) * 4;
    f32x4 v = *(const f32x4*)(x + i);
    bf16x4 o;
    o[0] = (__bf16)v[0]; o[1] = (__bf16)v[1]; o[2] = (__bf16)v[2]; o[3] = (__bf16)v[3];
    *(bf16x4*)(xb + i) = o;
    return;
  }
  __shared__ float t[32][33];
  int tb = bid - 8192;
  const float* src; __bf16* dst; int N;
  if (tb < 3072) { src = Wa; dst = wab; N = 3072; }
  else           { tb -= 3072; src = Wp; dst = wpb; N = 1024; }
  const int k0 = (tb & 31) * 32, n0 = (tb >> 5) * 32;
  const int c = tid & 31, r = tid >> 5;
#pragma unroll
  for (int i = 0; i < 4; ++i)
    t[r + i * 8][c] = src[(size_t)(k0 + r + i * 8) * N + n0 + c];
  __syncthreads();
#pragma unroll
  for (int i = 0; i < 4; ++i)
    dst[(size_t)(n0 + r + i * 8) * 1024 + k0 + c] = (__bf16)t[c][r + i * 8];
}

static constexpr int GK = 1024;
static constexpr int GNT = GK / 32;   // for the 128^2 ring-3 proj GEMM

// ---------- QKV GEMM: m201-style 8-phase, BM=BN=256, BK=64, 512 thr ----------
// 8 waves (2M x 4N), per-wave 128x64, acc[8][4]. LDS 128 KiB:
// As[buf][half][128*64], Bs[...] -- dbuf over K-tile parity (16 K-tiles).
// Per K-tile k (buf k&1), 4 phases x {ds_read frags | stage 1 half-tile ->
// barrier -> setprio(1) 16 MFMA setprio(0) -> barrier}:
//   P1: read A-lo(8) + B-lo(4); stage B0(k+1). MFMA Q00 (m0-3 x n0-1).
//   P2: read A-hi(8);           stage B1(k+1). MFMA Q10 (m4-7 x n0-1).
//   P3: read B-hi(4);           stage A0(k+2). MFMA Q01 (m0-3 x n2-3).
//   P4: (no reads);             stage A1(k+2). MFMA Q11 (m4-7 x n2-3).
//   vmcnt(4) at end of P4 (outstanding = A-halves of k+2 only) -- never 0
//   until k=14 (tail drain). Region-reuse safety: A(k) reads end P2 <
//   A(k+2) stages P3/P4; B(k) reads end P3 < B0(k+1)@P1-of-k+... each stage
//   lands >=1 barrier after the last read of the region it overwrites; buf
//   parity ensures stages of k+1 target the opposite buffer.
// Prologue: stage K0 full + A-halves of K1 (12 loads), vmcnt(4), barrier.
// Swizzle: LDS[row][g] holds global k-granule g^(row&7) (stage source XOR);
// reads XOR the same -- 16 lo-lanes land 2/bank (free; PMC-proven pattern).
// Grid 384 (32 bm x 12 bn), XCD-bijective, bn-major within XCD.
__global__ __launch_bounds__(512, 2) void k_gemm_qkv(const __bf16* __restrict__ A,
                                                     const __bf16* __restrict__ Bw,
                                                     const float* __restrict__ bias,
                                                     __bf16* __restrict__ qo,
                                                     __bf16* __restrict__ ko,
                                                     __bf16* __restrict__ vo) {
  __shared__ __bf16 As[2][2][128 * 64];   // [buf][half] 16 KiB each
  __shared__ __bf16 Bs[2][2][128 * 64];

  const int tid = threadIdx.x;
  const int wid = tid >> 6, lane = tid & 63;
  const int lo = lane & 15, hi = lane >> 4;
  const int wr = wid >> 2, wc = wid & 3;
  const int bhalf = wc >> 1;

  const int id = (int)blockIdx.x;
  const int wg = (id & 7) * 48 + (id >> 3);   // nwg = 384
  const int bm = wg / 12, bn = wg % 12;
  const int m0 = bm * 256, n0 = bn * 256;

  // staging: thread covers granules G=tid (row tid>>3, col tid&7) and
  // G=tid+512 (row 64+tid>>3) of each 128x64 half-tile; source col XOR'd.
  const int srow = tid >> 3;
  const int scs = (tid & 7) ^ (srow & 7);   // same for srow+64 (64%8==0)
  const __bf16* gA = A + (size_t)(m0 + srow) * GK + scs * 8;
  const __bf16* gB = Bw + (size_t)(n0 + srow) * GK + scs * 8;

#define STG_A(kt, hf, bufi)                                                  \
  {                                                                          \
    g2l16(gA + (size_t)((hf) * 128) * GK + (kt) * 64,                        \
          &As[bufi][hf][tid * 8]);                                           \
    g2l16(gA + (size_t)((hf) * 128 + 64) * GK + (kt) * 64,                   \
          &As[bufi][hf][4096 + tid * 8]);                                    \
  }
#define STG_B(kt, hf, bufi)                                                  \
  {                                                                          \
    g2l16(gB + (size_t)((hf) * 128) * GK + (kt) * 64,                        \
          &Bs[bufi][hf][tid * 8]);                                           \
    g2l16(gB + (size_t)((hf) * 128 + 64) * GK + (kt) * 64,                   \
          &Bs[bufi][hf][4096 + tid * 8]);                                    \
  }

  // fragment read offsets (elements): A row = mi*16+lo in half wr;
  // B row = (wc&1)*64 + nj*16 + lo in half wc>>1; k-granule (kk*4+hi)^(lo&7).
  const int gxl = lo & 7;
  const int arow = lo * 64;
  const int brow = ((wc & 1) * 64 + lo) * 64;
  int kofs[2];
#pragma unroll
  for (int kk = 0; kk < 2; ++kk) kofs[kk] = (((kk << 2) + hi) ^ gxl) * 8;

  f32x4 acc[8][4] = {};

  // prologue: K0 full + A-halves of K1; drain K0 (vmcnt 4), publish.
  STG_A(0, 0, 0); STG_A(0, 1, 0); STG_B(0, 0, 0); STG_B(0, 1, 0);
  STG_A(1, 0, 1); STG_A(1, 1, 1);
  asm volatile("s_waitcnt vmcnt(4)" ::: "memory");
  __builtin_amdgcn_s_barrier();
  __builtin_amdgcn_sched_barrier(0);

#pragma unroll 2
  for (int k = 0; k < 16; ++k) {
    const int cbuf = k & 1, nbuf = cbuf ^ 1;
    bf16x8 aL[4][2], aH[4][2], bL[2][2], bH[2][2];

    // ---- P1: read A-lo + B-lo; stage B0(k+1); MFMA Q00 ----
#pragma unroll
    for (int mi = 0; mi < 4; ++mi)
#pragma unroll
      for (int kk = 0; kk < 2; ++kk)
        aL[mi][kk] = *(const bf16x8*)&As[cbuf][wr][arow + mi * 1024 + kofs[kk]];
#pragma unroll
    for (int nj = 0; nj < 2; ++nj)
#pragma unroll
      for (int kk = 0; kk < 2; ++kk)
        bL[nj][kk] = *(const bf16x8*)&Bs[cbuf][bhalf][brow + nj * 1024 + kofs[kk]];
    if (k + 1 < 16) STG_B(k + 1, 0, nbuf);
    __builtin_amdgcn_s_barrier();
    __builtin_amdgcn_s_setprio(1);
#pragma unroll
    for (int mi = 0; mi < 4; ++mi)
#pragma unroll
      for (int nj = 0; nj < 2; ++nj)
#pragma unroll
        for (int kk = 0; kk < 2; ++kk)
          acc[mi][nj] = MFMA16(aL[mi][kk], bL[nj][kk], acc[mi][nj]);
    __builtin_amdgcn_s_setprio(0);
    __builtin_amdgcn_s_barrier();
    __builtin_amdgcn_sched_barrier(0);

    // ---- P2: read A-hi; stage B1(k+1); MFMA Q10 ----
#pragma unroll
    for (int mi = 0; mi < 4; ++mi)
#pragma unroll
      for (int kk = 0; kk < 2; ++kk)
        aH[mi][kk] = *(const bf16x8*)&As[cbuf][wr][arow + (mi + 4) * 1024 + kofs[kk]];
    if (k + 1 < 16) STG_B(k + 1, 1, nbuf);
    __builtin_amdgcn_s_barrier();
    __builtin_amdgcn_s_setprio(1);
#pragma unroll
    for (int mi = 0; mi < 4; ++mi)
#pragma unroll
      for (int nj = 0; nj < 2; ++nj)
#pragma unroll
        for (int kk = 0; kk < 2; ++kk)
          acc[mi + 4][nj] = MFMA16(aH[mi][kk], bL[nj][kk], acc[mi + 4][nj]);
    __builtin_amdgcn_s_setprio(0);
    __builtin_amdgcn_s_barrier();
    __builtin_amdgcn_sched_barrier(0);

    // ---- P3: read B-hi; stage A0(k+2); MFMA Q01 ----
#pragma unroll
    for (int nj = 0; nj < 2; ++nj)
#pragma unroll
      for (int kk = 0; kk < 2; ++kk)
        bH[nj][kk] = *(const bf16x8*)&Bs[cbuf][bhalf][brow + (nj + 2) * 1024 + kofs[kk]];
    if (k + 2 < 16) STG_A(k + 2, 0, cbuf);
    __builtin_amdgcn_s_barrier();
    __builtin_amdgcn_s_setprio(1);
#pragma unroll
    for (int mi = 0; mi < 4; ++mi)
#pragma unroll
      for (int nj = 0; nj < 2; ++nj)
#pragma unroll
        for (int kk = 0; kk < 2; ++kk)
          acc[mi][nj + 2] = MFMA16(aL[mi][kk], bH[nj][kk], acc[mi][nj + 2]);
    __builtin_amdgcn_s_setprio(0);
    __builtin_amdgcn_s_barrier();
    __builtin_amdgcn_sched_barrier(0);

    // ---- P4: stage A1(k+2); MFMA Q11; counted vmcnt; barrier ----
    if (k + 2 < 16) STG_A(k + 2, 1, cbuf);
    __builtin_amdgcn_s_barrier();
    __builtin_amdgcn_s_setprio(1);
#pragma unroll
    for (int mi = 0; mi < 4; ++mi)
#pragma unroll
      for (int nj = 0; nj < 2; ++nj)
#pragma unroll
        for (int kk = 0; kk < 2; ++kk)
          acc[mi + 4][nj + 2] = MFMA16(aH[mi][kk], bH[nj][kk], acc[mi + 4][nj + 2]);
    __builtin_amdgcn_s_setprio(0);
    if (k <= 13) {
      asm volatile("s_waitcnt vmcnt(4)" ::: "memory");
    } else if (k == 14) {
      asm volatile("s_waitcnt vmcnt(0)" ::: "memory");
    }
    if (k < 15) {
      __builtin_amdgcn_s_barrier();
      __builtin_amdgcn_sched_barrier(0);
    }
  }
#undef STG_A
#undef STG_B

  // epilogue: q (scaled) / k row-major; v transposed [bh][d][t'] with t'
  // bits 2<->3 swapped in 16-groups (flash PV identity).
#pragma unroll
  for (int nj = 0; nj < 4; ++nj) {
    int gn = n0 + wc * 64 + nj * 16 + lo;
    float bv = bias[gn];
    int which = gn >> 10;          // uniform per block (256 | 1024)
    int c = gn & 1023;
    int hh = c >> 6, d = c & 63;
#pragma unroll
    for (int mi = 0; mi < 8; ++mi) {
      int gm = m0 + wr * 128 + mi * 16 + hi * 4;
      int bb = gm >> 11, t0 = gm & 2047;
      if (which == 2) {
        int t0p = t0 ^ ((((t0 >> 2) ^ (t0 >> 3)) & 1) * 12);
        bf16x4 vv;
#pragma unroll
        for (int r = 0; r < 4; ++r) vv[r] = (__bf16)(acc[mi][nj][r] + bv);
        *(bf16x4*)(vo + ((size_t)(bb * 16 + hh) * 64 + d) * 2048 + t0p) = vv;
      } else {
#pragma unroll
        for (int r = 0; r < 4; ++r) {
          float val = acc[mi][nj][r] + bv;
          size_t idx = (((size_t)(bb * 16 + hh)) * 2048 + (t0 + r)) * 64 + d;
          if (which == 0)
            qo[idx] = (__bf16)(val * QSCALE);
          else
            ko[idx] = (__bf16)val;
        }
      }
    }
  }
}

// ---------------- proj GEMM: r8-proven 128^2 ring-3, unrolled ----------------
__global__ __launch_bounds__(256, 3) void k_gemm_proj(const __bf16* __restrict__ A,
                                                      const __bf16* __restrict__ Bw,
                                                      const float* __restrict__ bias,
                                                      float* __restrict__ out) {
  __shared__ __bf16 As[3][128 * 32];
  __shared__ __bf16 Bs[3][128 * 32];

  const int tid = threadIdx.x;
  const int wave = tid >> 6, lane = tid & 63;
  const int lo = lane & 15, hi = lane >> 4;
  const int wr = wave & 1, wc = wave >> 1;

  const int id = (int)blockIdx.x;
  const int wg = (id & 7) * 64 + (id >> 3);   // nwg = 512
  const int bm = wg / 8, bn = wg % 8;
  const int m0 = bm * 128, n0 = bn * 128;

  const int rG0 = tid >> 2, gG0 = (tid & 3) ^ ((rG0 >> 1) & 3);
  const int rG1 = (tid + 256) >> 2, gG1 = ((tid + 256) & 3) ^ ((rG1 >> 1) & 3);
  const __bf16* gaA0 = A + (size_t)(m0 + rG0) * GK + gG0 * 8;
  const __bf16* gaA1 = A + (size_t)(m0 + rG1) * GK + gG1 * 8;
  const __bf16* gbB0 = Bw + (size_t)(n0 + rG0) * GK + gG0 * 8;
  const __bf16* gbB1 = Bw + (size_t)(n0 + rG1) * GK + gG1 * 8;

  const int fsw = (hi ^ ((lo >> 1) & 3)) * 8;
  const int offA = (wr * 64 + lo) * 32 + fsw;
  const int offB = (wc * 64 + lo) * 32 + fsw;

  f32x4 acc[4][4] = {};

#define GSTAGE(jt, bufi)                                  \
  {                                                       \
    g2l16(gaA0 + (jt) * 32, &As[(bufi)][tid * 8]);        \
    g2l16(gaA1 + (jt) * 32, &As[(bufi)][2048 + tid * 8]); \
    g2l16(gbB0 + (jt) * 32, &Bs[(bufi)][tid * 8]);        \
    g2l16(gbB1 + (jt) * 32, &Bs[(bufi)][2048 + tid * 8]); \
  }

#define GMFMA(RB)                                                            \
  {                                                                          \
    bf16x8 af[4], bfr[4];                                                    \
    _Pragma("unroll")                                                        \
    for (int m = 0; m < 4; ++m)                                              \
      af[m] = *(const bf16x8*)&As[RB][offA + m * 512];                       \
    _Pragma("unroll")                                                        \
    for (int n = 0; n < 4; ++n)                                              \
      bfr[n] = *(const bf16x8*)&Bs[RB][offB + n * 512];                      \
    __builtin_amdgcn_s_setprio(1);                                           \
    _Pragma("unroll")                                                        \
    for (int m = 0; m < 4; ++m)                                              \
      _Pragma("unroll")                                                      \
      for (int n = 0; n < 4; ++n)                                            \
        acc[m][n] = MFMA16(af[m], bfr[n], acc[m][n]);                        \
    __builtin_amdgcn_s_setprio(0);                                           \
  }

#define GITER(RB, RS, JT)                            \
  {                                                  \
    GSTAGE((JT) + 2, RS);                            \
    GMFMA(RB);                                       \
    asm volatile("s_waitcnt vmcnt(4)" ::: "memory"); \
    __builtin_amdgcn_s_barrier();                    \
    __builtin_amdgcn_sched_barrier(0);               \
  }

  GSTAGE(0, 0);
  GSTAGE(1, 1);
  asm volatile("s_waitcnt vmcnt(4)" ::: "memory");
  __builtin_amdgcn_s_barrier();
  __builtin_amdgcn_sched_barrier(0);

#pragma unroll 1
  for (int j = 0; j < GNT - 2; j += 3) {
    GITER(0, 2, j);
    GITER(1, 0, j + 1);
    GITER(2, 1, j + 2);
  }
  GMFMA(0);
  asm volatile("s_waitcnt vmcnt(0)" ::: "memory");
  __builtin_amdgcn_s_barrier();
  __builtin_amdgcn_sched_barrier(0);
  GMFMA(1);

#undef GITER
#undef GMFMA
#undef GSTAGE

#pragma unroll
  for (int nj = 0; nj < 4; ++nj) {
    int gn = n0 + wc * 64 + nj * 16 + lo;
    float bv = bias[gn];
#pragma unroll
    for (int mi = 0; mi < 4; ++mi) {
      int gm = m0 + wr * 64 + mi * 16 + hi * 4;
#pragma unroll
      for (int r = 0; r < 4; ++r)
        out[(size_t)(gm + r) * 1024 + gn] = acc[mi][nj][r] + bv;
    }
  }
}

// ---------------- Flash attention (r9 version, verified) ----------------
__global__ __launch_bounds__(256, 2) void k_flash(const __bf16* __restrict__ qb,
                                                  const __bf16* __restrict__ kb,
                                                  const __bf16* __restrict__ vt,
                                                  __bf16* __restrict__ ob) {
  __shared__ __bf16 Ks[3][64 * 64];
  __shared__ __bf16 Vs[3][64 * 64];

  const int id = (int)blockIdx.x;
  const int xcd = id & 7, jj = id >> 3;
  const int bh = (jj & 7) * 8 + xcd;
  const int xsi = jj >> 3;
  const int xs = (xsi < 4) ? xsi : 11 - xsi;
  const int b = bh >> 4, h = bh & 15;
  const int tid = threadIdx.x, wave = tid >> 6, lane = tid & 63;
  const int l31 = lane & 31, hi32 = lane >> 5;
  const int gx = l31 & 7;

  const int qrow[2] = { (15 - xs) * 128 + wave * 32, xs * 128 + wave * 32 };

  bf16x8 qf[2][4];
#pragma unroll
  for (int rg = 0; rg < 2; ++rg) {
    const __bf16* Qp = qb + ((size_t)bh * kT + qrow[rg] + l31) * kHD + hi32 * 8;
#pragma unroll
    for (int ks = 0; ks < 4; ++ks)
      qf[rg][ks] = *(const bf16x8*)(Qp + ks * 16);
  }

  f32x16 acc[2][2] = {};
  float srow[2] = {0.0f, 0.0f};

  const __bf16* Kbase = kb + (size_t)bh * kT * kHD;
  const __bf16* Vbase = vt + (size_t)bh * kHD * kT;

  int srcK[2], srcV[2];
#pragma unroll
  for (int p = 0; p < 2; ++p) {
    int g = wave * 64 + lane + p * 256;
    int r = g >> 3, c = g & 7;
    int cs = c ^ (r & 7);
    srcK[p] = r * kHD + cs * 8;
    srcV[p] = r * kT + cs * 8;
  }

  const int nt = 32 - 2 * xs;

#pragma unroll
  for (int p = 0; p < 2; ++p) {
    g2l16(Kbase + srcK[p], &Ks[0][wave * 512 + p * 2048]);
    g2l16(Vbase + srcV[p], &Vs[0][wave * 512 + p * 2048]);
  }
#pragma unroll
  for (int p = 0; p < 2; ++p) {
    g2l16(Kbase + 64 * kHD + srcK[p], &Ks[1][wave * 512 + p * 2048]);
    g2l16(Vbase + 64 + srcV[p],       &Vs[1][wave * 512 + p * 2048]);
  }
  asm volatile("s_waitcnt vmcnt(4)" ::: "memory");
  __builtin_amdgcn_s_barrier();
  __builtin_amdgcn_sched_barrier(0);

  int rb = 0, rs = 2;
  for (int it = 0; it < nt; ++it) {
    const int kt = it * 64;
    const bool both = (it <= 2 * xs + 1);

    if (it + 2 < nt) {
      const int kn = kt + 128;
#pragma unroll
      for (int p = 0; p < 2; ++p) {
        g2l16(Kbase + kn * kHD + srcK[p], &Ks[rs][wave * 512 + p * 2048]);
        g2l16(Vbase + kn + srcV[p],       &Vs[rs][wave * 512 + p * 2048]);
      }
    }

    const __bf16* Kt = &Ks[rb][0];
    const __bf16* Vt = &Vs[rb][0];

    bf16x8 pa[2][4];

#pragma unroll
    for (int kb2 = 0; kb2 < 2; ++kb2) {
      bf16x8 ka[4];
#pragma unroll
      for (int ks = 0; ks < 4; ++ks)
        ka[ks] = *(const bf16x8*)&Kt[(kb2 * 32 + l31) * 64 +
                                     (((ks * 2 + hi32) ^ gx) * 8)];
#pragma unroll
      for (int rg = 0; rg < 2; ++rg) {
        if (rg == 1 && !both) break;
        f32x16 s = {};
        __builtin_amdgcn_s_setprio(1);
#pragma unroll
        for (int ks = 0; ks < 4; ++ks) s = MFMA32(ka[ks], qf[rg][ks], s);
        __builtin_amdgcn_s_setprio(0);
        const int qg = qrow[rg] + l31;
        const int kbs = kt + kb2 * 32 + 4 * hi32;
        if (kt + kb2 * 32 + 31 > qrow[rg]) {
#pragma unroll
          for (int i = 0; i < 16; ++i)
            if (kbs + (i & 3) + 8 * (i >> 2) > qg) s[i] = -INFINITY;
        }
#pragma unroll
        for (int i = 0; i < 16; ++i) s[i] = EXP2(s[i]);
        float sm = 0.0f;
#pragma unroll
        for (int i = 0; i < 16; ++i) sm += s[i];
        srow[rg] += sm;
#pragma unroll
        for (int a = 0; a < 2; ++a) {
          bf16x8 p;
#pragma unroll
          for (int e = 0; e < 8; ++e) p[e] = (__bf16)s[8 * a + e];
          pa[rg][kb2 * 2 + a] = p;
        }
      }
    }

    __builtin_amdgcn_s_setprio(1);
#pragma unroll
    for (int db = 0; db < 2; ++db) {
#pragma unroll
      for (int ks = 0; ks < 4; ++ks) {
        bf16x8 vb = *(const bf16x8*)&Vt[(db * 32 + l31) * 64 +
                                        (((ks * 2 + hi32) ^ gx) * 8)];
        acc[0][db] = MFMA32(pa[0][ks], vb, acc[0][db]);
        if (both) acc[1][db] = MFMA32(pa[1][ks], vb, acc[1][db]);
      }
    }
    __builtin_amdgcn_s_setprio(0);

    if (it + 2 < nt) {
      asm volatile("s_waitcnt vmcnt(4)" ::: "memory");
    } else if (it + 2 == nt) {
      asm volatile("s_waitcnt vmcnt(0)" ::: "memory");
    }
    if (it + 1 < nt) {
      __builtin_amdgcn_s_barrier();
      __builtin_amdgcn_sched_barrier(0);
    }
    rb = (rb == 2) ? 0 : rb + 1;
    rs = (rs == 2) ? 0 : rs + 1;
  }

#pragma unroll
  for (int rg = 0; rg < 2; ++rg) {
    float tot = srow[rg] + __shfl_xor(srow[rg], 32, 64);
    float invt = 1.0f / tot;
    __bf16* Op = ob + ((size_t)b * kT + qrow[rg]) * kC + h * kHD;
#pragma unroll
    for (int i = 0; i < 16; ++i) {
      int q = (i & 3) + 8 * (i >> 2) + 4 * hi32;
      float inv = __shfl(invt, q, 64);
      Op[(size_t)q * kC + l31]      = (__bf16)(acc[rg][0][i] * inv);
      Op[(size_t)q * kC + 32 + l31] = (__bf16)(acc[rg][1][i] * inv);
    }
  }
}

extern "C" void kernel_launch(void* const* d_in, const int* in_sizes, int n_in,
                              void* d_out, int out_size, void* d_ws, size_t ws_size,
                              hipStream_t stream) {
  const float* x      = (const float*)d_in[0];
  const float* W_attn = (const float*)d_in[1];
  const float* b_attn = (const float*)d_in[2];
  const float* W_proj = (const float*)d_in[3];
  const float* b_proj = (const float*)d_in[4];
  float* out = (float*)d_out;

  char* ws = (char*)d_ws;
  __bf16* xb  = (__bf16*)(ws + 0);          // [8192,1024]
  __bf16* ob  = (__bf16*)(ws + 0);          // alias: [B,T,C] flash out
  __bf16* wab = (__bf16*)(ws + 16777216);   // [3072,1024]
  __bf16* wpb = (__bf16*)(ws + 23068672);   // [1024,1024]
  __bf16* qbf = (__bf16*)(ws + 25165824);   // [B,H,T,hd]
  __bf16* kbf = (__bf16*)(ws + 41943040);   // [B,H,T,hd]
  __bf16* vtb = (__bf16*)(ws + 58720256);   // [B,H,hd,T'] (transposed V)

  k_prep<<<12288, 256, 0, stream>>>(x, xb, W_attn, wab, W_proj, wpb);
  k_gemm_qkv<<<dim3(384), 512, 0, stream>>>(xb, wab, b_attn, qbf, kbf, vtb);
  k_flash<<<dim3(512), 256, 0, stream>>>(qbf, kbf, vtb, ob);
  k_gemm_proj<<<dim3(512), 256, 0, stream>>>(ob, wpb, b_proj, out);
}